// Round 10
// baseline (1306.199 us; speedup 1.0000x reference)
//
#include <hip/hip_runtime.h>
#include <stdint.h>

#define BI 128
#define BT 128
#define KIMG 36
#define LCAP 64
#define DD 1024
#define MP 48        // imgs K padded to 3x16 for MFMA alignment
#define MB 96        // rows per block = 2 padded images
#define NB 512       // cols per block = 8 captions (wave = 2 captions)
#define ASLOTS 384   // A region 16B-slots (96 rows x 64 B)
#define ABYTES 6144
#define STG_BYTES 38912  // single staging buffer (A 6KB + B 32KB) -> 4 blocks/CU

typedef _Float16 h4 __attribute__((ext_vector_type(4)));
typedef _Float16 h8 __attribute__((ext_vector_type(8)));
typedef float f4 __attribute__((ext_vector_type(4)));

__device__ __forceinline__ float wave_red_sum(float v) {
#pragma unroll
  for (int o = 1; o < 64; o <<= 1) v += __shfl_xor(v, o, 64);
  return v;
}
__device__ __forceinline__ float wave_red_max(float v) {
#pragma unroll
  for (int o = 1; o < 64; o <<= 1) v = fmaxf(v, __shfl_xor(v, o, 64));
  return v;
}

// ---------------------------------------------------------------------------
// Kernel 1: add EPS, L2-normalize rows over D=1024, cast to fp16.
// imgs rows go to padded [BI][MP=48][DD] layout (rows 36..47 = 0).
// ---------------------------------------------------------------------------
__global__ __launch_bounds__(256) void norm_kernel(
    const float* __restrict__ imgs, const float* __restrict__ caps,
    _Float16* __restrict__ Ah, _Float16* __restrict__ Bh) {
  int row = blockIdx.x;
  int tid = threadIdx.x;
  const float* src;
  _Float16* dst;
  if (row < BI * MP) {
    int i = row / MP, k = row - i * MP;
    dst = Ah + (size_t)row * DD;
    if (k >= KIMG) {           // zero padding rows (block-uniform branch)
      h4 z = {};
      ((h4*)dst)[tid] = z;
      return;
    }
    src = imgs + ((size_t)i * KIMG + k) * DD;
  } else {
    int r = row - BI * MP;
    dst = Bh + (size_t)r * DD;
    src = caps + (size_t)r * DD;
  }
  float4 x = ((const float4*)src)[tid];
  x.x += 1e-6f; x.y += 1e-6f; x.z += 1e-6f; x.w += 1e-6f;
  float ss = x.x * x.x + x.y * x.y + x.z * x.z + x.w * x.w;
  ss = wave_red_sum(ss);
  __shared__ float red[4];
  int lane = tid & 63, w = tid >> 6;
  if (lane == 0) red[w] = ss;
  __syncthreads();
  float scale = rsqrtf(red[0] + red[1] + red[2] + red[3]);
  h4 o;
  o[0] = (_Float16)(x.x * scale);
  o[1] = (_Float16)(x.y * scale);
  o[2] = (_Float16)(x.z * scale);
  o[3] = (_Float16)(x.w * scale);
  ((h4*)dst)[tid] = o;
}

// ---------------------------------------------------------------------------
// Kernel 2: 2 images x 8 captions per block (96x512 tile), wave = 2 captions
// (per-wave 96x128: 494 LDS-bytes/MFMA vs 661 at 96x64).
// SINGLE-buffered LDS (38.9 KB) -> 4 blocks/CU, grid 1024 = fully resident.
// Naive in-block schedule (STAGE -> vmcnt0+barrier -> compute -> barrier);
// cross-BLOCK TLP (16 waves/CU) covers the drain — the only mechanism that
// has ever paid on this kernel (R3/R7 vs R4/R5/R6/R8/R9).
// Swizzle: 16B-slot involution s ^= (s>>3)&7 per region; LDS dest linear,
// global source pre-swizzled (rule 21), frag reads apply same involution.
// ---------------------------------------------------------------------------
__global__ __launch_bounds__(256, 4) void sims_kernel(
    const _Float16* __restrict__ Ah, const _Float16* __restrict__ Bh,
    const int* __restrict__ img_lens, const int* __restrict__ cap_lens,
    float* __restrict__ out) {
  __shared__ char stage[STG_BYTES] __attribute__((aligned(16)));

  int tid = threadIdx.x;
  int lane = tid & 63;
  int w = tid >> 6;       // wave: cols [128w,128w+128) = captions {2w,2w+1}

  int wgid = blockIdx.x;  // grid 1024, all resident
  int bx = wgid & 15;     // caption octet 0..15
  int by = wgid >> 4;     // image pair 0..63

  int fr = lane & 15;
  int fq = lane >> 4;

  const size_t arow0 = (size_t)by * MB;
  const size_t brow0 = (size_t)bx * NB;

  // ---- staging: 38 chunks of 1 KB (A:0-5, B:6-37); wave w takes c=w+4*it --
  const int nit = (w < 2) ? 10 : 9;
  const _Float16* gp[10];
  int ldsb[10];
#pragma unroll
  for (int it = 0; it < 10; ++it) {
    int c = w + 4 * it;
    if (c < 38) {
      int s = c * 64 + lane;
      bool isA = c < 6;
      int srel = isA ? s : s - ASLOTS;
      int sw = srel ^ ((srel >> 3) & 7);
      gp[it] = (isA ? Ah + arow0 * DD : Bh + brow0 * DD) +
               (size_t)(sw >> 2) * DD + (sw & 3) * 8;
      ldsb[it] = c * 1024 + lane * 16;
    }
  }

  // ---- swizzled fragment byte offsets (k-invariant) ----
  int aoff[6], boff[8];
#pragma unroll
  for (int mi = 0; mi < 6; ++mi) {
    int s = (16 * mi + fr) * 4 + fq;
    aoff[mi] = (s ^ ((s >> 3) & 7)) * 16;
  }
#pragma unroll
  for (int ni = 0; ni < 8; ++ni) {
    int s = (128 * w + 16 * ni + fr) * 4 + fq;
    boff[ni] = ABYTES + (s ^ ((s >> 3) & 7)) * 16;
  }

  f4 acc[6][8] = {};

  for (int t = 0; t < 32; ++t) {
    int k0 = 32 * t;
#pragma unroll
    for (int it = 0; it < 10; ++it) {
      if (it < nit) {
        __builtin_amdgcn_global_load_lds(
            (const __attribute__((address_space(1))) void*)(gp[it] + k0),
            (__attribute__((address_space(3))) void*)(stage + ldsb[it]),
            16, 0, 0);
      }
    }
    asm volatile("s_waitcnt vmcnt(0)" ::: "memory");
    __builtin_amdgcn_s_barrier();        // all waves' stage landed
    __builtin_amdgcn_sched_barrier(0);

    h8 af[6];
#pragma unroll
    for (int mi = 0; mi < 6; ++mi)
      af[mi] = *(const h8*)(stage + aoff[mi]);
#pragma unroll
    for (int half = 0; half < 2; ++half) {
      h8 bf[4];
#pragma unroll
      for (int ni = 0; ni < 4; ++ni)
        bf[ni] = *(const h8*)(stage + boff[4 * half + ni]);
#pragma unroll
      for (int mi = 0; mi < 6; ++mi)
#pragma unroll
        for (int ni = 0; ni < 4; ++ni)
          acc[mi][4 * half + ni] = __builtin_amdgcn_mfma_f32_16x16x32_f16(
              af[mi], bf[ni], acc[mi][4 * half + ni], 0, 0, 0);
    }
    // reads retired (compiler lgkm-waits precede the MFMAs); barrier frees
    // the buffer for next step's STAGE.
    __builtin_amdgcn_s_barrier();
    __builtin_amdgcn_sched_barrier(0);
  }

  // ---- register epilogue: C/D col=16*ni'+fr, row=16*mi'+4*fq+j ----
#pragma unroll
  for (int img = 0; img < 2; ++img) {
    int Ki = img_lens[2 * by + img];
#pragma unroll
    for (int tn = 0; tn < 2; ++tn) {
      int t = bx * 8 + 2 * w + tn;
      int Lt = cap_lens[t];

      float m = -1e30f;
#pragma unroll
      for (int mi = 0; mi < 3; ++mi)
#pragma unroll
        for (int ni = 0; ni < 4; ++ni)
#pragma unroll
          for (int j = 0; j < 4; ++j) {
            bool valid = (16 * mi + 4 * fq + j < Ki) && (16 * ni + fr < Lt);
            if (valid) m = fmaxf(m, acc[3 * img + mi][4 * tn + ni][j]);
          }
      m = wave_red_max(m);

      float rowe[3][4] = {}, rowes[3][4] = {}, cole[4] = {}, coles[4] = {};
#pragma unroll
      for (int mi = 0; mi < 3; ++mi)
#pragma unroll
        for (int ni = 0; ni < 4; ++ni)
#pragma unroll
          for (int j = 0; j < 4; ++j) {
            float s = acc[3 * img + mi][4 * tn + ni][j];
            bool valid = (16 * mi + 4 * fq + j < Ki) && (16 * ni + fr < Lt);
            float e = valid ? __expf((s - m) * 20.0f) : 0.f;  // 1/LAMB = 20
            float es = e * s;
            rowe[mi][j] += e;
            rowes[mi][j] += es;
            cole[ni] += e;
            coles[ni] += es;
          }

      // v2t: per row, reduce over cols (fr lanes), then accumulate rows
      float part = 0.f;
#pragma unroll
      for (int mi = 0; mi < 3; ++mi)
#pragma unroll
        for (int j = 0; j < 4; ++j) {
          float Re = rowe[mi][j], Res = rowes[mi][j];
#pragma unroll
          for (int o = 1; o < 16; o <<= 1) {
            Re += __shfl_xor(Re, o, 64);
            Res += __shfl_xor(Res, o, 64);
          }
          int row = 16 * mi + 4 * fq + j;
          if (fr == 0 && row < Ki) part += (Res / Re) * (0.5f / (float)Ki);
        }
      // t2v: per col, reduce over rows (fq lanes), then accumulate cols
#pragma unroll
      for (int ni = 0; ni < 4; ++ni) {
        float Ce = cole[ni], Ces = coles[ni];
#pragma unroll
        for (int o = 16; o < 64; o <<= 1) {
          Ce += __shfl_xor(Ce, o, 64);
          Ces += __shfl_xor(Ces, o, 64);
        }
        int l = 16 * ni + fr;
        if (fq == 0 && l < Lt) part += (Ces / Ce) * (0.5f / (float)Lt);
      }
      float sim = wave_red_sum(part);
      if (lane == 0) out[(size_t)(2 * by + img) * BT + t] = sim;
    }
  }
}

extern "C" void kernel_launch(void* const* d_in, const int* in_sizes, int n_in,
                              void* d_out, int out_size, void* d_ws, size_t ws_size,
                              hipStream_t stream) {
  // setup_inputs order: img_cls, imgs, cap_cls, caps, img_lens, cap_lens
  const float* imgs = (const float*)d_in[1];
  const float* caps = (const float*)d_in[3];
  const int* img_lens = (const int*)d_in[4];
  const int* cap_lens = (const int*)d_in[5];
  float* out = (float*)d_out;

  _Float16* Ah = (_Float16*)d_ws;                    // [BI*MP][DD] = 12.6 MB
  _Float16* Bh = Ah + (size_t)BI * MP * DD;          // [BT*LCAP][DD] = 16.8 MB

  norm_kernel<<<BI * MP + BT * LCAP, 256, 0, stream>>>(imgs, caps, Ah, Bh);
  sims_kernel<<<1024, 256, 0, stream>>>(Ah, Bh, img_lens, cap_lens, out);
}

// Round 11
// 141.166 us; speedup vs baseline: 9.2529x; 9.2529x over previous
//
#include <hip/hip_runtime.h>
#include <stdint.h>

#define BI 128
#define BT 128
#define KIMG 36
#define LCAP 64
#define DD 1024
#define MP 48        // imgs K padded to 3x16 for MFMA alignment
#define MB 96        // rows per block = 2 padded images
#define NB 256       // cols per block = 4 captions
#define ABUF 6144    // one A staging buffer: 96 rows x 64 B

typedef _Float16 h4 __attribute__((ext_vector_type(4)));
typedef _Float16 h8 __attribute__((ext_vector_type(8)));
typedef float f4 __attribute__((ext_vector_type(4)));

__device__ __forceinline__ float wave_red_sum(float v) {
#pragma unroll
  for (int o = 1; o < 64; o <<= 1) v += __shfl_xor(v, o, 64);
  return v;
}
__device__ __forceinline__ float wave_red_max(float v) {
#pragma unroll
  for (int o = 1; o < 64; o <<= 1) v = fmaxf(v, __shfl_xor(v, o, 64));
  return v;
}

// ---------------------------------------------------------------------------
// Kernel 1: add EPS, L2-normalize rows over D=1024, cast to fp16.
// imgs -> padded row-major [BI*MP][DD] (rows 36..47 of each image = 0).
// caps -> FRAGMENT-MAJOR Bh: tile (r/16, k/32) of 512 halves; within a tile
// half-offset = lane*8 where lane = (kk>>3)*16 + (r&15), kk = k&31. This makes
// a GEMM wave's bf[ni] fragment load one contiguous, coalesced 1 KB segment.
// ---------------------------------------------------------------------------
__global__ __launch_bounds__(256) void norm_kernel(
    const float* __restrict__ imgs, const float* __restrict__ caps,
    _Float16* __restrict__ Ah, _Float16* __restrict__ Bh) {
  int row = blockIdx.x;
  int tid = threadIdx.x;
  const float* src;
  bool isCap;
  int r = 0;
  if (row < BI * MP) {
    int i = row / MP, k = row - i * MP;
    isCap = false;
    if (k >= KIMG) {           // zero padding rows (block-uniform branch)
      h4 z = {};
      ((h4*)(Ah + (size_t)row * DD))[tid] = z;
      return;
    }
    src = imgs + ((size_t)i * KIMG + k) * DD;
  } else {
    r = row - BI * MP;
    isCap = true;
    src = caps + (size_t)r * DD;
  }
  float4 x = ((const float4*)src)[tid];
  x.x += 1e-6f; x.y += 1e-6f; x.z += 1e-6f; x.w += 1e-6f;
  float ss = x.x * x.x + x.y * x.y + x.z * x.z + x.w * x.w;
  ss = wave_red_sum(ss);
  __shared__ float red[4];
  int lane = tid & 63, w = tid >> 6;
  if (lane == 0) red[w] = ss;
  __syncthreads();
  float scale = rsqrtf(red[0] + red[1] + red[2] + red[3]);
  h4 o;
  o[0] = (_Float16)(x.x * scale);
  o[1] = (_Float16)(x.y * scale);
  o[2] = (_Float16)(x.z * scale);
  o[3] = (_Float16)(x.w * scale);
  if (!isCap) {
    ((h4*)(Ah + (size_t)row * DD))[tid] = o;
  } else {
    int k = 4 * tid;
    size_t tile = (size_t)(r >> 4) * 32 + (k >> 5);
    int sub = ((k >> 3) & 3) * 128 + (r & 15) * 8 + (k & 7);
    *(h4*)(Bh + tile * 512 + sub) = o;
  }
}

// ---------------------------------------------------------------------------
// Kernel 2: 2 images x 4 captions per block (96x256), wave w = caption w.
// Champion 2-phase skeleton (R3/R7), but B NEVER TOUCHES LDS:
//  - A (shared by 4 waves): swizzled LDS dbuf, 6 KB/step (12.3 KB total).
//  - B (wave-private): fragment-major coalesced 1KB global->VGPR loads,
//    ping-pong prefetched one step ahead; issued before compute so the
//    end-of-step __syncthreads drain is latency-covered (as in champion).
// LDS demand/block-step: 62.5 KB -> 30 KB. 3 blocks/CU via VGPR<=170.
// A swizzle: 16B-slot involution s ^= (s>>3)&7; LDS dest linear, global
// source pre-swizzled (rule 21), frag reads apply same involution.
// ---------------------------------------------------------------------------
__global__ __launch_bounds__(256, 3) void sims_kernel(
    const _Float16* __restrict__ Ah, const _Float16* __restrict__ Bh,
    const int* __restrict__ img_lens, const int* __restrict__ cap_lens,
    float* __restrict__ out) {
  __shared__ char stage[2 * ABUF] __attribute__((aligned(16)));

  int tid = threadIdx.x;
  int lane = tid & 63;
  int w = tid >> 6;       // wave = caption within quad

  // ---- XCD-aware remap (R7): 4 caption-quads per XCD, by shared x4 ----
  int wgid = blockIdx.x;
  int xcd = wgid & 7;
  int slot = wgid >> 3;            // 0..255
  int bx = 4 * xcd + (slot & 3);   // caption quad 0..31
  int by = slot >> 2;              // image pair 0..63

  int fr = lane & 15;
  int fq = lane >> 4;

  const size_t arow0 = (size_t)by * MB;
  const size_t brow0 = (size_t)bx * NB;

  // ---- A staging: 6 chunks of 1 KB; waves own {0-1},{2-3},{4},{5} ----
  const int c0 = (w < 2) ? 2 * w : w + 2;
  const int nch = (w < 2) ? 2 : 1;
  int s0 = c0 * 64 + lane;
  int sw0 = s0 ^ ((s0 >> 3) & 7);
  const _Float16* gpA = Ah + (arow0 + (sw0 >> 2)) * DD + (sw0 & 3) * 8;
  const int lds0 = c0 * 1024 + lane * 16;

  // ---- af LDS read base: swizzle XOR is mi-invariant (64mi ≡ 0 mod 8) ----
  int sl = 4 * fr + fq;
  const int aoff0 = (sl ^ ((sl >> 3) & 7)) * 16;

  // ---- B fragment-major pointers: frag(ni, t) at bp[ni] + 512*t halves ----
  const _Float16* bp[4];
#pragma unroll
  for (int ni = 0; ni < 4; ++ni)
    bp[ni] = Bh + ((size_t)((bx * 16) + 4 * w + ni) * 32) * 512 + lane * 8;

  f4 acc[6][4] = {};
  h8 bfA[4], bfB[4];

  auto STAGE = [&](int buf, int k0) {
    __builtin_amdgcn_global_load_lds(
        (const __attribute__((address_space(1))) void*)(gpA + k0),
        (__attribute__((address_space(3))) void*)(stage + buf * ABUF + lds0), 16, 0, 0);
    if (nch == 2)
      __builtin_amdgcn_global_load_lds(
          (const __attribute__((address_space(1))) void*)(gpA + 16 * DD + k0),
          (__attribute__((address_space(3))) void*)(stage + buf * ABUF + lds0 + 1024), 16, 0, 0);
  };
  auto LOADB = [&](h8(&bf)[4], int t) {
#pragma unroll
    for (int ni = 0; ni < 4; ++ni) bf[ni] = *(const h8*)(bp[ni] + 512 * t);
  };
  // one step: prefetch A(t+1)+B(t+1), compute(t), barrier (drains prefetch)
  auto BODY = [&](int t, int parity, h8(&cur)[4], h8(&nxt)[4]) {
    if (t < 31) {
      STAGE(parity ^ 1, 32 * (t + 1));   // buf(t+1): reads of it at t-1 done
      LOADB(nxt, t + 1);
    }
    const char* rb = stage + parity * ABUF;
    h8 af[6];
#pragma unroll
    for (int mi = 0; mi < 6; ++mi)
      af[mi] = *(const h8*)(rb + aoff0 + 1024 * mi);
    __builtin_amdgcn_s_setprio(1);
#pragma unroll
    for (int mi = 0; mi < 6; ++mi)
#pragma unroll
      for (int ni = 0; ni < 4; ++ni)
        acc[mi][ni] = __builtin_amdgcn_mfma_f32_16x16x32_f16(
            af[mi], cur[ni], acc[mi][ni], 0, 0, 0);
    __builtin_amdgcn_s_setprio(0);
    __syncthreads();   // vmcnt(0)+barrier: A(t+1)/B(t+1) had full compute to land
  };

  // ---- prologue: A(0)->buf0, B(0)->regs ----
  STAGE(0, 0);
  LOADB(bfA, 0);
  __syncthreads();

  for (int tt = 0; tt < 32; tt += 2) {
    BODY(tt, 0, bfA, bfB);
    BODY(tt + 1, 1, bfB, bfA);
  }

  // ---- register epilogue: C/D layout col=16*ni+fr, row=16*mi+4*fq+j ----
  int t = bx * 4 + w;
  int Lt = cap_lens[t];

#pragma unroll
  for (int img = 0; img < 2; ++img) {
    int Ki = img_lens[2 * by + img];

    float m = -1e30f;
#pragma unroll
    for (int mi = 0; mi < 3; ++mi)
#pragma unroll
      for (int ni = 0; ni < 4; ++ni)
#pragma unroll
        for (int j = 0; j < 4; ++j) {
          bool valid = (16 * mi + 4 * fq + j < Ki) && (16 * ni + fr < Lt);
          if (valid) m = fmaxf(m, acc[3 * img + mi][ni][j]);
        }
    m = wave_red_max(m);

    float rowe[3][4] = {}, rowes[3][4] = {}, cole[4] = {}, coles[4] = {};
#pragma unroll
    for (int mi = 0; mi < 3; ++mi)
#pragma unroll
      for (int ni = 0; ni < 4; ++ni)
#pragma unroll
        for (int j = 0; j < 4; ++j) {
          float s = acc[3 * img + mi][ni][j];
          bool valid = (16 * mi + 4 * fq + j < Ki) && (16 * ni + fr < Lt);
          float e = valid ? __expf((s - m) * 20.0f) : 0.f;  // 1/LAMB = 20
          float es = e * s;
          rowe[mi][j] += e;
          rowes[mi][j] += es;
          cole[ni] += e;
          coles[ni] += es;
        }

    // v2t: per row, reduce over cols (fr lanes), then accumulate rows
    float part = 0.f;
#pragma unroll
    for (int mi = 0; mi < 3; ++mi)
#pragma unroll
      for (int j = 0; j < 4; ++j) {
        float Re = rowe[mi][j], Res = rowes[mi][j];
#pragma unroll
        for (int o = 1; o < 16; o <<= 1) {
          Re += __shfl_xor(Re, o, 64);
          Res += __shfl_xor(Res, o, 64);
        }
        int row = 16 * mi + 4 * fq + j;
        if (fr == 0 && row < Ki) part += (Res / Re) * (0.5f / (float)Ki);
      }
    // t2v: per col, reduce over rows (fq lanes), then accumulate cols
#pragma unroll
    for (int ni = 0; ni < 4; ++ni) {
      float Ce = cole[ni], Ces = coles[ni];
#pragma unroll
      for (int o = 16; o < 64; o <<= 1) {
        Ce += __shfl_xor(Ce, o, 64);
        Ces += __shfl_xor(Ces, o, 64);
      }
      int l = 16 * ni + fr;
      if (fq == 0 && l < Lt) part += (Ces / Ce) * (0.5f / (float)Lt);
    }
    float sim = wave_red_sum(part);
    if (lane == 0) out[(size_t)(2 * by + img) * BT + t] = sim;
  }
}

extern "C" void kernel_launch(void* const* d_in, const int* in_sizes, int n_in,
                              void* d_out, int out_size, void* d_ws, size_t ws_size,
                              hipStream_t stream) {
  // setup_inputs order: img_cls, imgs, cap_cls, caps, img_lens, cap_lens
  const float* imgs = (const float*)d_in[1];
  const float* caps = (const float*)d_in[3];
  const int* img_lens = (const int*)d_in[4];
  const int* cap_lens = (const int*)d_in[5];
  float* out = (float*)d_out;

  _Float16* Ah = (_Float16*)d_ws;                    // [BI*MP][DD] = 12.6 MB
  _Float16* Bh = Ah + (size_t)BI * MP * DD;          // fragment-major, 16.8 MB

  norm_kernel<<<BI * MP + BT * LCAP, 256, 0, stream>>>(imgs, caps, Ah, Bh);
  sims_kernel<<<2048, 256, 0, stream>>>(Ah, Bh, img_lens, cap_lens, out);
}